// Round 13
// baseline (272.342 us; speedup 1.0000x reference)
//
#include <hip/hip_runtime.h>

// TvarLayer: out[b, (n*C+c)*9+k, l] = (p_k*W[n,c,k] - mean_k(p*W))^2 / sum_k(W[n,c,k]) + Bbias[n,c]
// B=4, N=8, C=8, K=9, H=W=128, L=16384. Out 151 MB f32.
//
// Ledger (JSON = kernel + ~91us poison fill + ~26us misc; anchor: R7's 200us row):
//   R2  occupancy x8     -> NULL      R5  NT->cached   -> -4us (kernel ~37us, 4.4 TB/s)
//   R7  plane-per-block  -> 200us, WRITE_SIZE 5x       R9  double-write -> +2.6us (L2 merges)
//   R10 XCD-sharding     -> NULL
// R11: fill-mimic write order. The 6.35 TB/s fill's unique property: chip-wide
//      time-ordered writes form ONE dense window sweeping linearly. Mimic exactly:
//      thread (bid,tid) iter it writes output float4 #((bid+it*4608)*256+tid).
//      Block-iteration = 1/16 plane -> weights stay block-uniform; patch/mean
//      recomputed per k (VALU ~6us, reads L2-resident -> hidden under write stream).

#define BB 4
#define NN 8
#define CC 8
#define KK 9
#define HH 128
#define WW 128
#define LL (HH * WW)
#define GRID 4608
#define ITERS 8   // GRID*256*ITERS = 9,437,184 = total output float4s

typedef float vf4 __attribute__((ext_vector_type(4)));

__global__ __launch_bounds__(256) void tvar_kernel(
    const float* __restrict__ arr,
    const float* __restrict__ Wt,
    const float* __restrict__ Bb,
    float* __restrict__ out)
{
    const int tid = threadIdx.x;
    vf4* __restrict__ of4 = (vf4*)out;

    #pragma unroll
    for (int it = 0; it < ITERS; ++it) {
        const int B0    = blockIdx.x + it * GRID;   // 0..36863, plane-aligned
        const int plane = B0 >> 4;                  // (b*64+nc)*9+k, block-uniform
        const int l4    = ((B0 & 15) << 8) | tid;   // 0..4095 within plane
        const int bnc   = plane / 9;                // uniform (magic mul)
        const int k     = plane - bnc * 9;
        const int nc    = bnc & 63;
        const int b     = bnc >> 6;
        const int c     = nc & 7;
        const int h     = l4 >> 5;
        const int ws    = (l4 & 31) << 2;

        // block-uniform weights -> scalar loads
        const float* wrow = Wt + nc * KK;
        float w9[KK];
        float wsum = 0.f;
        #pragma unroll
        for (int kk = 0; kk < KK; ++kk) { w9[kk] = wrow[kk]; wsum += w9[kk]; }
        const float sinv = 1.0f / wsum;
        const float bias = Bb[nc];
        const float wk   = w9[k];
        const int kh = k / 3, kw = k - kh * 3;      // uniform

        // 3x6 zero-padded patch around (h, ws-1..ws+4)
        const float* abase = arr + (size_t)((b * CC + c) * HH) * WW;
        float p[3][6];
        #pragma unroll
        for (int r = 0; r < 3; ++r) {
            const int hh = h + r - 1;
            if (hh >= 0 && hh < HH) {
                const float* row = abase + hh * WW + ws;
                const float4 v = *(const float4*)row;      // 16B-aligned
                p[r][1] = v.x; p[r][2] = v.y; p[r][3] = v.z; p[r][4] = v.w;
                p[r][0] = (ws > 0)      ? row[-1] : 0.f;
                p[r][5] = (ws + 4 < WW) ? row[4]  : 0.f;
            } else {
                #pragma unroll
                for (int j = 0; j < 6; ++j) p[r][j] = 0.f;
            }
        }

        float mean[4] = {0.f, 0.f, 0.f, 0.f};
        #pragma unroll
        for (int kk = 0; kk < KK; ++kk) {
            const int rh = kk / 3, rw = kk - rh * 3;
            #pragma unroll
            for (int j = 0; j < 4; ++j)
                mean[j] += p[rh][j + rw] * w9[kk];
        }

        const float inv9 = 1.0f / 9.0f;
        vf4 o;
        #pragma unroll
        for (int j = 0; j < 4; ++j) {
            const float v = p[kh][j + kw] * wk;
            const float d = v - mean[j] * inv9;
            o[j] = d * d * sinv + bias;
        }
        // dense chip-wide sweep: consecutive global thread -> consecutive 16B,
        // marching forward by 18 MiB per iteration (byte-for-byte the fill pattern)
        of4[(size_t)B0 * 256 + tid] = o;
    }
}

extern "C" void kernel_launch(void* const* d_in, const int* in_sizes, int n_in,
                              void* d_out, int out_size, void* d_ws, size_t ws_size,
                              hipStream_t stream) {
    const float* arr = (const float*)d_in[0];
    const float* Wt  = (const float*)d_in[1];
    const float* Bb  = (const float*)d_in[2];
    float* out = (float*)d_out;

    tvar_kernel<<<GRID, 256, 0, stream>>>(arr, Wt, Bb, out);
}